// Round 1
// baseline (258.723 us; speedup 1.0000x reference)
//
#include <hip/hip_runtime.h>

// Problem constants
constexpr int Hd = 512;
constexpr int Bd = 64;
constexpr int Sd = 2048;

constexpr int BM = 128;
constexpr int BN = 128;
constexpr int BK = 32;
constexpr int LDP = BK + 8;   // padded LDS stride (40 bf16 = 80B): conflict-minimal b128 reads

typedef __bf16 bf16x8 __attribute__((ext_vector_type(8)));
typedef float  f32x4  __attribute__((ext_vector_type(4)));

__device__ __forceinline__ unsigned short f2bf(float f){
  // native cast -> compiler emits v_cvt_pk_bf16_f32 for pairs (RNE)
  __bf16 h = (__bf16)f;
  return __builtin_bit_cast(unsigned short, h);
}

__device__ __forceinline__ float fast_tanh(float x){
  // tanh(x) = 1 - 2/(e^{2x}+1); v_exp_f32 + v_rcp_f32, saturates correctly at +-inf
  float e = __expf(2.0f * x);
  return 1.0f - 2.0f * __builtin_amdgcn_rcpf(e + 1.0f);
}

// q[b,o] = bq[o] + sum_h query[b,h] * Wq[o,h]
__global__ __launch_bounds__(256) void qproj_kernel(const float* __restrict__ query,
                                                    const float* __restrict__ Wq,
                                                    const float* __restrict__ bq,
                                                    float* __restrict__ qout){
  int b   = blockIdx.x;
  int tid = threadIdx.x;
  __shared__ float qs[Hd];
  for (int i = tid; i < Hd; i += 256) qs[i] = query[b*Hd + i];
  __syncthreads();
  for (int o = tid; o < Hd; o += 256){
    const float* w = Wq + o*Hd;
    float s = 0.f;
    #pragma unroll 4
    for (int k = 0; k < Hd; k += 4){
      f32x4 wv = *(const f32x4*)(w + k);
      s += wv[0]*qs[k] + wv[1]*qs[k+1] + wv[2]*qs[k+2] + wv[3]*qs[k+3];
    }
    qout[b*Hd + o] = s + bq[o];
  }
}

// Per batch b: C[o][s] = sum_h Wr[o][h] * ref[b][s][h]  (M=512, N=2048, K=512)
// Output ref_t[b][o][s] row-major == C row-major. Fused: logits[b][s] += V.tanh(q+C+br)
__global__ __launch_bounds__(256) void fused_kernel(const float* __restrict__ ref,
                                                    const float* __restrict__ Wr,
                                                    const float* __restrict__ br,
                                                    const float* __restrict__ V,
                                                    const float* __restrict__ qbuf,
                                                    float* __restrict__ out,     // [B][H][S]
                                                    float* __restrict__ logits){ // [B][S]
  const int bid = blockIdx.x;
  const int mt  = bid & 3;          // fastest: 4 m-tiles share one ref panel (L2/L3 reuse)
  const int nt  = (bid >> 2) & 15;
  const int bb  = bid >> 6;
  const int m0  = mt * BM;
  const int n0  = nt * BN;

  const int tid  = threadIdx.x;
  const int lane = tid & 63;
  const int wave = tid >> 6;
  const int wm   = wave >> 1;   // 2x2 wave grid, each wave owns 64x64 of C
  const int wn   = wave & 1;

  __shared__ unsigned short As[BM][LDP];
  __shared__ unsigned short Bs[BN][LDP];

  f32x4 acc[4][4];
  #pragma unroll
  for (int i = 0; i < 4; ++i)
    #pragma unroll
    for (int j = 0; j < 4; ++j)
      acc[i][j] = f32x4{0.f, 0.f, 0.f, 0.f};

  const int sr = tid >> 3;        // staging row 0..31 (4 passes of 32 rows)
  const int sk = (tid & 7) * 4;   // staging col 0,4,...,28

  const float* Aglob = Wr  + (size_t)(m0 + sr)*Hd + sk;
  const float* Bglob = ref + ((size_t)bb*Sd + (n0 + sr))*Hd + sk;

  const int rofs = lane & 15;
  const int koff = (lane >> 4) * 8;

  for (int kt = 0; kt < Hd; kt += BK){
    // ---- stage A (Wr tile) and B (ref tile) as bf16 into padded LDS ----
    #pragma unroll
    for (int it = 0; it < 4; ++it){
      f32x4 v = *(const f32x4*)(Aglob + (size_t)it*32*Hd + kt);
      unsigned p0 = (unsigned)f2bf(v[0]) | ((unsigned)f2bf(v[1]) << 16);
      unsigned p1 = (unsigned)f2bf(v[2]) | ((unsigned)f2bf(v[3]) << 16);
      uint2 pk; pk.x = p0; pk.y = p1;
      *(uint2*)(&As[sr + it*32][sk]) = pk;
    }
    #pragma unroll
    for (int it = 0; it < 4; ++it){
      f32x4 v = *(const f32x4*)(Bglob + (size_t)it*32*Hd + kt);
      unsigned p0 = (unsigned)f2bf(v[0]) | ((unsigned)f2bf(v[1]) << 16);
      unsigned p1 = (unsigned)f2bf(v[2]) | ((unsigned)f2bf(v[3]) << 16);
      uint2 pk; pk.x = p0; pk.y = p1;
      *(uint2*)(&Bs[sr + it*32][sk]) = pk;
    }
    __syncthreads();

    // ---- fragments: lane holds row (lane&15), k = (lane>>4)*8 + j ----
    bf16x8 a[4], bfr[4];
    #pragma unroll
    for (int mi = 0; mi < 4; ++mi)
      a[mi] = *(const bf16x8*)(&As[wm*64 + mi*16 + rofs][koff]);
    #pragma unroll
    for (int ni = 0; ni < 4; ++ni)
      bfr[ni] = *(const bf16x8*)(&Bs[wn*64 + ni*16 + rofs][koff]);

    #pragma unroll
    for (int mi = 0; mi < 4; ++mi)
      #pragma unroll
      for (int ni = 0; ni < 4; ++ni)
        acc[mi][ni] = __builtin_amdgcn_mfma_f32_16x16x32_bf16(a[mi], bfr[ni], acc[mi][ni], 0, 0, 0);
    __syncthreads();
  }

  // ---- epilogue: +br, store ref_t, fused tanh/V column sums ----
  const int col0 = n0 + wn*64;
  const int row0 = m0 + wm*64;
  const int cl   = lane & 15;          // C/D: col = lane&15
  const int rgrp = (lane >> 4) * 4;    //      row = (lane>>4)*4 + j
  const float* qrow = qbuf + bb*Hd;
  float colsum[4] = {0.f, 0.f, 0.f, 0.f};
  float* outb = out + (size_t)bb*Hd*Sd;

  #pragma unroll
  for (int mi = 0; mi < 4; ++mi){
    #pragma unroll
    for (int j = 0; j < 4; ++j){
      int o = row0 + mi*16 + rgrp + j;
      float brv = br[o];
      float qv  = qrow[o];
      float vv  = V[o];
      float* orow = outb + (size_t)o*Sd + col0;
      #pragma unroll
      for (int ni = 0; ni < 4; ++ni){
        float c = acc[mi][ni][j] + brv;
        orow[ni*16 + cl] = c;
        colsum[ni] += vv * fast_tanh(qv + c);
      }
    }
  }

  // reduce over the wave's 64 rows: lanes sharing (lane&15) are l, l^16, l^32, l^48
  #pragma unroll
  for (int ni = 0; ni < 4; ++ni){
    colsum[ni] += __shfl_xor(colsum[ni], 16);
    colsum[ni] += __shfl_xor(colsum[ni], 32);
  }
  if (lane < 16){
    float* lrow = logits + (size_t)bb*Sd + col0;
    #pragma unroll
    for (int ni = 0; ni < 4; ++ni)
      atomicAdd(lrow + ni*16 + cl, colsum[ni]);
  }
}

extern "C" void kernel_launch(void* const* d_in, const int* in_sizes, int n_in,
                              void* d_out, int out_size, void* d_ws, size_t ws_size,
                              hipStream_t stream){
  const float* query = (const float*)d_in[0];
  const float* ref   = (const float*)d_in[1];
  const float* Wq    = (const float*)d_in[2];
  const float* bq    = (const float*)d_in[3];
  const float* Wr    = (const float*)d_in[4];
  const float* br    = (const float*)d_in[5];
  const float* V     = (const float*)d_in[6];

  float* out    = (float*)d_out;
  float* logits = out + (size_t)Bd*Hd*Sd;   // second output, concatenated flat
  float* qbuf   = (float*)d_ws;             // [B][H] f32 = 128 KB

  qproj_kernel<<<Bd, 256, 0, stream>>>(query, Wq, bq, qbuf);
  hipMemsetAsync(logits, 0, (size_t)Bd*Sd*sizeof(float), stream);

  // grid: 64 batches x (16 n-tiles x 4 m-tiles)
  fused_kernel<<<Bd*64, 256, 0, stream>>>(ref, Wr, br, V, qbuf, out, logits);
}

// Round 2
// 177.578 us; speedup vs baseline: 1.4570x; 1.4570x over previous
//
#include <hip/hip_runtime.h>

// Problem constants
constexpr int Hd = 512;
constexpr int Bd = 64;
constexpr int Sd = 2048;

constexpr int BM = 128;
constexpr int BN = 128;
constexpr int BK = 32;
constexpr int LDP = BK + 4;   // 72B row stride = 18 banks: fragment rows hit distinct banks

typedef __bf16 bf16x8 __attribute__((ext_vector_type(8)));
typedef float  f32x4  __attribute__((ext_vector_type(4)));

struct StageRegs { f32x4 a[4]; f32x4 b[4]; };

__device__ __forceinline__ unsigned short f2bf(float f){
  __bf16 h = (__bf16)f;
  return __builtin_bit_cast(unsigned short, h);
}

__device__ __forceinline__ float fast_tanh(float x){
  // tanh(x) = 1 - 2/(e^{2x}+1); saturates correctly
  float e = __expf(2.0f * x);
  return 1.0f - 2.0f * __builtin_amdgcn_rcpf(e + 1.0f);
}

// q[b,o] = bq[o] + sum_h query[b,h] * Wq[o,h]; grid (B, 4), 128 thr
__global__ __launch_bounds__(128) void qproj_kernel(const float* __restrict__ query,
                                                    const float* __restrict__ Wq,
                                                    const float* __restrict__ bq,
                                                    float* __restrict__ qout){
  int b   = blockIdx.x;
  int og  = blockIdx.y;
  int tid = threadIdx.x;
  __shared__ float qs[Hd];
  for (int i = tid; i < Hd; i += 128) qs[i] = query[b*Hd + i];
  __syncthreads();
  int o = og*128 + tid;
  const float* w = Wq + (size_t)o*Hd;
  float s = 0.f;
  #pragma unroll 4
  for (int k = 0; k < Hd; k += 4){
    f32x4 wv = *(const f32x4*)(w + k);
    s += wv[0]*qs[k] + wv[1]*qs[k+1] + wv[2]*qs[k+2] + wv[3]*qs[k+3];
  }
  qout[b*Hd + o] = s + bq[o];
}

__device__ __forceinline__ void issue_loads(StageRegs& s, const float* Ag, const float* Bg, int kt){
  #pragma unroll
  for (int it = 0; it < 4; ++it) s.a[it] = *(const f32x4*)(Ag + (size_t)it*32*Hd + kt);
  #pragma unroll
  for (int it = 0; it < 4; ++it) s.b[it] = *(const f32x4*)(Bg + (size_t)it*32*Hd + kt);
}

__device__ __forceinline__ void write_stage(const StageRegs& s,
                                            unsigned short (*As)[LDP],
                                            unsigned short (*Bs)[LDP],
                                            int sr, int sk){
  #pragma unroll
  for (int it = 0; it < 4; ++it){
    uint2 pk;
    pk.x = (unsigned)f2bf(s.a[it][0]) | ((unsigned)f2bf(s.a[it][1]) << 16);
    pk.y = (unsigned)f2bf(s.a[it][2]) | ((unsigned)f2bf(s.a[it][3]) << 16);
    *(uint2*)(&As[sr + it*32][sk]) = pk;
  }
  #pragma unroll
  for (int it = 0; it < 4; ++it){
    uint2 pk;
    pk.x = (unsigned)f2bf(s.b[it][0]) | ((unsigned)f2bf(s.b[it][1]) << 16);
    pk.y = (unsigned)f2bf(s.b[it][2]) | ((unsigned)f2bf(s.b[it][3]) << 16);
    *(uint2*)(&Bs[sr + it*32][sk]) = pk;
  }
}

// Per batch b: C[o][s] = sum_h Wr[o][h] * ref[b][s][h]; fused tanh/V logits
__global__ __launch_bounds__(256, 3) void fused_kernel(const float* __restrict__ ref,
                                                       const float* __restrict__ Wr,
                                                       const float* __restrict__ br,
                                                       const float* __restrict__ V,
                                                       const float* __restrict__ qbuf,
                                                       float* __restrict__ out,     // [B][H][S]
                                                       float* __restrict__ logits){ // [B][S]
  // Bijective XCD swizzle (nwg=4096, divisible by 8): the 4 mt-blocks sharing one
  // ref panel get consecutive slots on the SAME XCD -> panel fetched from HBM once.
  const int bid = blockIdx.x;
  const int wid = (bid & 7) * (gridDim.x >> 3) + (bid >> 3);
  const int mt  = wid & 3;
  const int nt  = (wid >> 2) & 15;
  const int bb  = wid >> 6;
  const int m0  = mt * BM;
  const int n0  = nt * BN;

  const int tid  = threadIdx.x;
  const int lane = tid & 63;
  const int wave = tid >> 6;
  const int wm   = wave >> 1;   // 2x2 wave grid, each wave owns 64x64 of C
  const int wn   = wave & 1;

  __shared__ unsigned short As[BM][LDP];
  __shared__ unsigned short Bs[BN][LDP];

  f32x4 acc[4][4];
  #pragma unroll
  for (int i = 0; i < 4; ++i)
    #pragma unroll
    for (int j = 0; j < 4; ++j)
      acc[i][j] = f32x4{0.f, 0.f, 0.f, 0.f};

  const int sr = tid >> 3;        // staging row 0..31 (4 passes of 32 rows)
  const int sk = (tid & 7) * 4;   // staging col 0,4,...,28

  const float* Aglob = Wr  + (size_t)(m0 + sr)*Hd + sk;
  const float* Bglob = ref + ((size_t)bb*Sd + (n0 + sr))*Hd + sk;

  const int rofs = lane & 15;
  const int koff = (lane >> 4) * 8;

  StageRegs sA, sB;
  issue_loads(sA, Aglob, Bglob, 0);

  #pragma unroll 1
  for (int kt = 0; kt < Hd; kt += 2*BK){
    // ---------- sub-step 1: compute tile kt (sA), prefetch kt+BK into sB ----------
    write_stage(sA, As, Bs, sr, sk);
    issue_loads(sB, Aglob, Bglob, kt + BK);     // stays in flight across raw barriers
    asm volatile("s_waitcnt lgkmcnt(0)" ::: "memory");
    __builtin_amdgcn_s_barrier();
    {
      bf16x8 a[4], bfr[4];
      #pragma unroll
      for (int mi = 0; mi < 4; ++mi)
        a[mi] = *(const bf16x8*)(&As[wm*64 + mi*16 + rofs][koff]);
      #pragma unroll
      for (int ni = 0; ni < 4; ++ni)
        bfr[ni] = *(const bf16x8*)(&Bs[wn*64 + ni*16 + rofs][koff]);
      #pragma unroll
      for (int mi = 0; mi < 4; ++mi)
        #pragma unroll
        for (int ni = 0; ni < 4; ++ni)
          acc[mi][ni] = __builtin_amdgcn_mfma_f32_16x16x32_bf16(a[mi], bfr[ni], acc[mi][ni], 0, 0, 0);
    }
    asm volatile("s_waitcnt lgkmcnt(0)" ::: "memory");
    __builtin_amdgcn_s_barrier();

    // ---------- sub-step 2: compute tile kt+BK (sB), prefetch kt+2BK into sA ----------
    write_stage(sB, As, Bs, sr, sk);
    {
      int nk = (kt + 2*BK < Hd) ? (kt + 2*BK) : 0;  // clamp: last prefetch is discarded
      issue_loads(sA, Aglob, Bglob, nk);
    }
    asm volatile("s_waitcnt lgkmcnt(0)" ::: "memory");
    __builtin_amdgcn_s_barrier();
    {
      bf16x8 a[4], bfr[4];
      #pragma unroll
      for (int mi = 0; mi < 4; ++mi)
        a[mi] = *(const bf16x8*)(&As[wm*64 + mi*16 + rofs][koff]);
      #pragma unroll
      for (int ni = 0; ni < 4; ++ni)
        bfr[ni] = *(const bf16x8*)(&Bs[wn*64 + ni*16 + rofs][koff]);
      #pragma unroll
      for (int mi = 0; mi < 4; ++mi)
        #pragma unroll
        for (int ni = 0; ni < 4; ++ni)
          acc[mi][ni] = __builtin_amdgcn_mfma_f32_16x16x32_bf16(a[mi], bfr[ni], acc[mi][ni], 0, 0, 0);
    }
    asm volatile("s_waitcnt lgkmcnt(0)" ::: "memory");
    __builtin_amdgcn_s_barrier();
  }

  // ---- epilogue: +br, NT-store ref_t, fused tanh/V column sums ----
  const int col0 = n0 + wn*64;
  const int row0 = m0 + wm*64;
  const int cl   = lane & 15;          // C/D: col = lane&15
  const int rgrp = (lane >> 4) * 4;    //      row = (lane>>4)*4 + j
  const float* qrow = qbuf + bb*Hd;
  float colsum[4] = {0.f, 0.f, 0.f, 0.f};
  float* outb = out + (size_t)bb*Hd*Sd;

  #pragma unroll
  for (int mi = 0; mi < 4; ++mi){
    #pragma unroll
    for (int j = 0; j < 4; ++j){
      int o = row0 + mi*16 + rgrp + j;
      float brv = br[o];
      float qv  = qrow[o];
      float vv  = V[o];
      float* orow = outb + (size_t)o*Sd + col0;
      #pragma unroll
      for (int ni = 0; ni < 4; ++ni){
        float c = acc[mi][ni][j] + brv;
        __builtin_nontemporal_store(c, &orow[ni*16 + cl]);  // don't thrash L2/L3
        colsum[ni] += vv * fast_tanh(qv + c);
      }
    }
  }

  // reduce over the wave's 64 rows: lanes sharing (lane&15) are l, l^16, l^32, l^48
  #pragma unroll
  for (int ni = 0; ni < 4; ++ni){
    colsum[ni] += __shfl_xor(colsum[ni], 16);
    colsum[ni] += __shfl_xor(colsum[ni], 32);
  }
  if (lane < 16){
    float* lrow = logits + (size_t)bb*Sd + col0;
    #pragma unroll
    for (int ni = 0; ni < 4; ++ni)
      atomicAdd(lrow + ni*16 + cl, colsum[ni]);
  }
}

extern "C" void kernel_launch(void* const* d_in, const int* in_sizes, int n_in,
                              void* d_out, int out_size, void* d_ws, size_t ws_size,
                              hipStream_t stream){
  const float* query = (const float*)d_in[0];
  const float* ref   = (const float*)d_in[1];
  const float* Wq    = (const float*)d_in[2];
  const float* bq    = (const float*)d_in[3];
  const float* Wr    = (const float*)d_in[4];
  const float* br    = (const float*)d_in[5];
  const float* V     = (const float*)d_in[6];

  float* out    = (float*)d_out;
  float* logits = out + (size_t)Bd*Hd*Sd;   // second output, concatenated flat
  float* qbuf   = (float*)d_ws;             // [B][H] f32 = 128 KB

  hipMemsetAsync(logits, 0, (size_t)Bd*Sd*sizeof(float), stream);
  qproj_kernel<<<dim3(Bd, 4), 128, 0, stream>>>(query, Wq, bq, qbuf);

  // grid: 64 batches x (16 n-tiles x 4 m-tiles), XCD-swizzled in-kernel
  fused_kernel<<<Bd*64, 256, 0, stream>>>(ref, Wr, br, V, qbuf, out, logits);
}